// Round 3
// baseline (400.735 us; speedup 1.0000x reference)
//
#include <hip/hip_runtime.h>

typedef unsigned short u16;
typedef __attribute__((ext_vector_type(8))) __bf16 bf16x8;
typedef __attribute__((ext_vector_type(4))) float f32x4;
typedef __attribute__((ext_vector_type(8))) unsigned short u16x8;

#define AS1 __attribute__((address_space(1)))
#define AS3 __attribute__((address_space(3)))

// blob layout (u16 element offsets) -- bf16 copies of GEMM inputs
#define OB_X    0L
#define OB_H    4194304L
#define OB_WI   8388608L
#define OB_WF   10485760L
#define OB_WO   12582912L
#define OB_WXS  14680064L
#define OB_WXG  15728640L
#define OB_WHG  16777216L
#define BLOB_EL 17825792L

__device__ __forceinline__ u16 f2b(float f) {
    unsigned u = __float_as_uint(f);
    u += 0x7fffu + ((u >> 16) & 1u);   // round-to-nearest-even
    return (u16)(u >> 16);
}

// ---------------- f32 -> bf16 blob build ----------------
__global__ __launch_bounds__(256) void convert_all(
    const float* __restrict__ x, const float* __restrict__ h,
    const float* __restrict__ Wi, const float* __restrict__ Wf,
    const float* __restrict__ Wo, const float* __restrict__ Wxs,
    const float* __restrict__ Wxg, const float* __restrict__ Whg,
    u16* __restrict__ blob)
{
    long e = ((long)blockIdx.x * 256 + threadIdx.x) * 8;
    const float* src; long off;
    if      (e < OB_H)   { src = x;   off = e; }
    else if (e < OB_WI)  { src = h;   off = e - OB_H; }
    else if (e < OB_WF)  { src = Wi;  off = e - OB_WI; }
    else if (e < OB_WO)  { src = Wf;  off = e - OB_WF; }
    else if (e < OB_WXS) { src = Wo;  off = e - OB_WO; }
    else if (e < OB_WXG) { src = Wxs; off = e - OB_WXS; }
    else if (e < OB_WHG) { src = Wxg; off = e - OB_WXG; }
    else                 { src = Whg; off = e - OB_WHG; }
    f32x4 v0 = *(const f32x4*)(src + off);
    f32x4 v1 = *(const f32x4*)(src + off + 4);
    u16x8 o;
    o[0] = f2b(v0.x); o[1] = f2b(v0.y); o[2] = f2b(v0.z); o[3] = f2b(v0.w);
    o[4] = f2b(v1.x); o[5] = f2b(v1.y); o[6] = f2b(v1.z); o[7] = f2b(v1.w);
    *(u16x8*)(blob + e) = o;
}

__device__ __forceinline__ float sigf(float z) {
    return 1.f / (1.f + __expf(-z));
}

// ---- staging pieces (512 threads; er = t>>3 in [0,64), 16B/thread/load) ----
// XOR-swizzled SOURCE granule (gsw) + linear LDS dest; read side applies same XOR.
__device__ __forceinline__ void stage_A(u16* An, int kS, const u16* aLo,
                                        const u16* aHi, int t, int er, int gsw) {
    const u16* aSrc = ((kS < 1024) ? aLo : aHi) + (kS & 1023) + gsw;
#pragma unroll
    for (int it = 0; it < 4; ++it)
        __builtin_amdgcn_global_load_lds(
            (AS1 void*)(aSrc + (it * 64 + er) * 1024),
            (AS3 void*)(An + (it * 512 + t) * 8), 16, 0, 0);
}

__device__ __forceinline__ void stage_Bseg(u16* dst, const u16* src,
                                           int t, int er, int gsw, int ld) {
    __builtin_amdgcn_global_load_lds(
        (AS1 void*)(src + er * ld + gsw),
        (AS3 void*)(dst + t * 8), 16, 0, 0);
}

// ---- one K=32 half-step of MFMA (verified fragment mapping, unchanged) ----
__device__ __forceinline__ void compute_half(
    const u16* As, const u16* Bs, int kk, bool seg4,
    int wm, int wn, int fr, int fq, int r7, f32x4 (&acc)[5][4][2])
{
    const int sw = ((((kk >> 3) + fq) ^ r7) << 3);
    bf16x8 a[4];
#pragma unroll
    for (int mi = 0; mi < 4; ++mi)
        a[mi] = *(const bf16x8*)(As + (wm + mi * 16 + fr) * 64 + sw);
    __builtin_amdgcn_s_setprio(1);
#pragma unroll
    for (int s = 0; s < 4; ++s) {
        bf16x8 b0 = *(const bf16x8*)(Bs + s * 4096 + (wn + fr) * 64 + sw);
        bf16x8 b1 = *(const bf16x8*)(Bs + s * 4096 + (wn + 16 + fr) * 64 + sw);
#pragma unroll
        for (int mi = 0; mi < 4; ++mi) {
            acc[s][mi][0] = __builtin_amdgcn_mfma_f32_16x16x32_bf16(
                a[mi], b0, acc[s][mi][0], 0, 0, 0);
            acc[s][mi][1] = __builtin_amdgcn_mfma_f32_16x16x32_bf16(
                a[mi], b1, acc[s][mi][1], 0, 0, 0);
        }
    }
    if (seg4) {                        // seg 4 (Wxs) has K=1024
        bf16x8 b0 = *(const bf16x8*)(Bs + 16384 + (wn + fr) * 64 + sw);
        bf16x8 b1 = *(const bf16x8*)(Bs + 16384 + (wn + 16 + fr) * 64 + sw);
#pragma unroll
        for (int mi = 0; mi < 4; ++mi) {
            acc[4][mi][0] = __builtin_amdgcn_mfma_f32_16x16x32_bf16(
                a[mi], b0, acc[4][mi][0], 0, 0, 0);
            acc[4][mi][1] = __builtin_amdgcn_mfma_f32_16x16x32_bf16(
                a[mi], b1, acc[4][mi][1], 0, 0, 0);
        }
    }
    __builtin_amdgcn_s_setprio(0);
}

// ---- one K-tile with counted-vmcnt pipelining (T4) ----
// Entering: up to 9 outstanding loads belong to cur (issued last tile).
// P1 issues 5 loads for nxt -> vmcnt(5) waits exactly the old 9 -> barrier ->
// compute kk=0. P2 issues remaining 4 -> compute kk=32 -> trailing barrier
// (NO waitcnt: the 9 in-flight loads for nxt stay in flight across it).
template<bool STAGE, int VMC>
__device__ __forceinline__ void tile_step(
    const u16* Ac, const u16* Bc, u16* An, u16* Bn,
    int k0, int kS,
    const u16* aLo, const u16* aHi,
    const u16* w0, const u16* w1, const u16* w2,
    const u16* w3lo, const u16* w3hi, const u16* w4,
    int t, int er, int gsw,
    int wm, int wn, int fr, int fq, int r7,
    f32x4 (&acc)[5][4][2])
{
    // ---------------- P1 ----------------
    if (STAGE) {
        stage_A(An, kS, aLo, aHi, t, er, gsw);
        stage_Bseg(Bn, w0 + kS, t, er, gsw, 2048);
    }
    // Pin: all issues above MUST precede the counted wait (vmcnt accounting).
    __builtin_amdgcn_sched_barrier(0);
    asm volatile("s_waitcnt vmcnt(%0)" :: "n"(VMC) : "memory");
    __builtin_amdgcn_s_barrier();
    __builtin_amdgcn_sched_barrier(0);
    compute_half(Ac, Bc, 0, k0 < 1024, wm, wn, fr, fq, r7, acc);
    // ---------------- P2 ----------------
    if (STAGE) {
        stage_Bseg(Bn + 4096,  w1 + kS, t, er, gsw, 2048);
        stage_Bseg(Bn + 8192,  w2 + kS, t, er, gsw, 2048);
        const u16* w3 = (kS < 1024) ? (w3lo + kS) : (w3hi + (kS - 1024));
        stage_Bseg(Bn + 12288, w3, t, er, gsw, 1024);
        // seg4 unused for kS>=1024: stage a harmless dummy to keep 9 loads/tile
        stage_Bseg(Bn + 16384, w4 + (kS & 1023), t, er, gsw, 1024);
    }
    compute_half(Ac, Bc, 32, k0 < 1024, wm, wn, fr, fq, r7, acc);
    // Pin: P2's issues precede the trailing barrier (accounting for next tile).
    __builtin_amdgcn_sched_barrier(0);
    __builtin_amdgcn_s_barrier();      // raw barrier: NO vmcnt drain
    __builtin_amdgcn_sched_barrier(0);
}

// ---------------- fully-fused SRU-LSTM cell, counted-vmcnt 2-phase ----------------
// Block = 512 threads (8 waves, 4m x 2n), tile 256m x 64j x 5 segs, BK=64.
// Grid 16x16 = 256 blocks = 1 block/CU (144 KB LDS dbuf), 2 waves/SIMD.
__global__ __launch_bounds__(512, 2) void srulstm_fused(
    const u16* __restrict__ blob,
    const float* __restrict__ c_prev,
    const float* __restrict__ bi, const float* __restrict__ bfv,
    const float* __restrict__ bo, const float* __restrict__ bxs,
    const float* __restrict__ bxg, const float* __restrict__ bhg,
    float* __restrict__ out)
{
    __shared__ __align__(16) u16 As[2][256 * 64];       // 2 x 32 KB
    __shared__ __align__(16) u16 Bs[2][5 * 64 * 64];    // 2 x 40 KB

    const u16* x = blob + OB_X;
    const u16* h = blob + OB_H;

    const int t = threadIdx.x;
    const int j0 = blockIdx.x * 64;    // 16 j-slices
    const int m0 = blockIdx.y * 256;   // 16 m-tiles

    const u16* w0   = blob + OB_WI  + j0 * 2048;
    const u16* w1   = blob + OB_WF  + j0 * 2048;
    const u16* w2   = blob + OB_WO  + j0 * 2048;
    const u16* w3lo = blob + OB_WXG + j0 * 1024;
    const u16* w3hi = blob + OB_WHG + j0 * 1024;
    const u16* w4   = blob + OB_WXS + j0 * 1024;

    const u16* aLo = x + m0 * 1024;
    const u16* aHi = h + m0 * 1024;

    const int lane = t & 63;
    const int wave = t >> 6;           // 0..7
    const int wm = (wave >> 1) << 6;   // 0/64/128/192
    const int wn = (wave & 1) << 5;    // 0/32
    const int fr = lane & 15;
    const int fq = lane >> 4;
    const int r7 = fr & 7;

    const int er = t >> 3;             // staging row in 64-row chunk (0..63)
    const int gsw = (((t & 7) ^ (er & 7)) << 3);

    f32x4 acc[5][4][2] = {};           // [seg][mi][ni]

    // prologue: fill buffer 0 (9 loads in flight; first tile's vmcnt(5) waits them)
    stage_A(As[0], 0, aLo, aHi, t, er, gsw);
    stage_Bseg(Bs[0],         w0, t, er, gsw, 2048);
    stage_Bseg(Bs[0] + 4096,  w1, t, er, gsw, 2048);
    stage_Bseg(Bs[0] + 8192,  w2, t, er, gsw, 2048);
    stage_Bseg(Bs[0] + 12288, w3lo, t, er, gsw, 1024);
    stage_Bseg(Bs[0] + 16384, w4, t, er, gsw, 1024);

    for (int k0 = 0; k0 < 2048; k0 += 128) {
        tile_step<true, 5>(As[0], Bs[0], As[1], Bs[1], k0, k0 + 64,
                           aLo, aHi, w0, w1, w2, w3lo, w3hi, w4,
                           t, er, gsw, wm, wn, fr, fq, r7, acc);
        if (k0 + 128 < 2048)
            tile_step<true, 5>(As[1], Bs[1], As[0], Bs[0], k0 + 64, k0 + 128,
                               aLo, aHi, w0, w1, w2, w3lo, w3hi, w4,
                               t, er, gsw, wm, wn, fr, fq, r7, acc);
        else
            tile_step<false, 0>(As[1], Bs[1], As[0], Bs[0], k0 + 64, 0,
                                aLo, aHi, w0, w1, w2, w3lo, w3hi, w4,
                                t, er, gsw, wm, wn, fr, fq, r7, acc);
    }

    // ---- in-register LSTM epilogue ----
    // C/D layout (m89): lane holds D[m=fq*4+r][n=fr]; all 5 segs aligned.
    const int orow = m0 + wm + (fq << 2);
    const int ocol = j0 + wn + fr;
#pragma unroll
    for (int ni = 0; ni < 2; ++ni) {
        const int col = ocol + ni * 16;
        const float bi_v = bi[col],  bf_v = bfv[col], bo_v = bo[col];
        const float bs_v = bxs[col], bg_v = bxg[col], bh_v = bhg[col];
#pragma unroll
        for (int mi = 0; mi < 4; ++mi) {
#pragma unroll
            for (int r = 0; r < 4; ++r) {
                const long idx = (long)(orow + mi * 16 + r) * 1024 + col;
                const float cp = c_prev[idx];
                const float i_t = sigf(acc[0][mi][ni][r] + bi_v);
                const float f_t = sigf(acc[1][mi][ni][r] + bf_v);
                const float o_t = sigf(acc[2][mi][ni][r] + bo_v);
                const float cand = acc[3][mi][ni][r] + bg_v + bh_v;
                const float s_t  = acc[4][mi][ni][r] + bs_v;
                const float g_t = tanhf(s_t * cand);
                const float c_t = f_t * cp + i_t * g_t;
                const float h_t = o_t * tanhf(c_t);
                out[idx] = h_t;                    // h_t
                out[4194304L + idx] = c_t;         // c_t
            }
        }
    }
}

extern "C" void kernel_launch(void* const* d_in, const int* in_sizes, int n_in,
                              void* d_out, int out_size, void* d_ws, size_t ws_size,
                              hipStream_t stream)
{
    u16* blob = (u16*)d_ws;            // 35.7 MB
    float* out = (float*)d_out;

    const long convBlocks = BLOB_EL / 8 / 256;     // 8704

    convert_all<<<dim3(convBlocks), dim3(256), 0, stream>>>(
        (const float*)d_in[0], (const float*)d_in[1], (const float*)d_in[3],
        (const float*)d_in[5], (const float*)d_in[7], (const float*)d_in[9],
        (const float*)d_in[11], (const float*)d_in[13], blob);

    srulstm_fused<<<dim3(16, 16), dim3(512), 0, stream>>>(
        blob, (const float*)d_in[2], (const float*)d_in[4], (const float*)d_in[6],
        (const float*)d_in[8], (const float*)d_in[10], (const float*)d_in[12],
        (const float*)d_in[14], out);
}

// Round 6
// 225.715 us; speedup vs baseline: 1.7754x; 1.7754x over previous
//
#include <hip/hip_runtime.h>

typedef unsigned short u16;
typedef __attribute__((ext_vector_type(8))) __bf16 bf16x8;
typedef __attribute__((ext_vector_type(4))) float f32x4;
typedef __attribute__((ext_vector_type(4))) unsigned short u16x4;

#define AS1 __attribute__((address_space(1)))
#define AS3 __attribute__((address_space(3)))

// blob layout (u16 element offsets) -- bf16 copies of GEMM inputs
#define OB_X    0L
#define OB_H    4194304L
#define OB_WI   8388608L
#define OB_WF   10485760L
#define OB_WO   12582912L
#define OB_WXS  14680064L
#define OB_WXG  15728640L
#define OB_WHG  16777216L
#define BLOB_EL 17825792L

__device__ __forceinline__ u16 f2b(float f) {
    unsigned u = __float_as_uint(f);
    u += 0x7fffu + ((u >> 16) & 1u);   // round-to-nearest-even
    return (u16)(u >> 16);
}

// ---------------- f32 -> bf16 blob build (dtypes verified r3-r5) ----------------
__global__ __launch_bounds__(256) void convert_all(
    const float* __restrict__ x, const float* __restrict__ h,
    const float* __restrict__ Wi, const float* __restrict__ Wf,
    const float* __restrict__ Wo, const float* __restrict__ Wxs,
    const float* __restrict__ Wxg, const float* __restrict__ Whg,
    u16* __restrict__ blob)
{
    long e = ((long)blockIdx.x * 256 + threadIdx.x) * 8;
    const float* src; long off;
    if      (e < OB_H)   { src = x;   off = e; }
    else if (e < OB_WI)  { src = h;   off = e - OB_H; }
    else if (e < OB_WF)  { src = Wi;  off = e - OB_WI; }
    else if (e < OB_WO)  { src = Wf;  off = e - OB_WF; }
    else if (e < OB_WXS) { src = Wo;  off = e - OB_WO; }
    else if (e < OB_WXG) { src = Wxs; off = e - OB_WXS; }
    else if (e < OB_WHG) { src = Wxg; off = e - OB_WXG; }
    else                 { src = Whg; off = e - OB_WHG; }
    f32x4 v0 = *(const f32x4*)(src + off);
    f32x4 v1 = *(const f32x4*)(src + off + 4);
    u16x4 o0, o1;
    o0.x = f2b(v0.x); o0.y = f2b(v0.y); o0.z = f2b(v0.z); o0.w = f2b(v0.w);
    o1.x = f2b(v1.x); o1.y = f2b(v1.y); o1.z = f2b(v1.z); o1.w = f2b(v1.w);
    *(u16x4*)(blob + e) = o0;
    *(u16x4*)(blob + e + 4) = o1;
}

__device__ __forceinline__ void stageB(u16* dst, const u16* src, int ld,
                                       int t, int er, int gsw) {
#pragma unroll
    for (int it = 0; it < 2; ++it) {
        const int row = it * 32 + er;
        __builtin_amdgcn_global_load_lds(
            (AS1 void*)(src + row * ld + gsw),
            (AS3 void*)(dst + (it * 256 + t) * 8), 16, 0, 0);
    }
}

__device__ __forceinline__ float sigf(float z) {
    return 1.f / (1.f + __expf(-z));
}

// ---------------- fully-fused SRU-LSTM cell ----------------
// Block = 128 m-rows x 64 j-cols, ALL 5 gate segments (i,f,o,cand,s):
// per K-iter stage one A-tile (128x64) + five B-tiles (64x64 each), 5x MFMA
// per staged A-byte vs the r5 split-N GEMM (barrier amortization 2.9x better).
// Seg accumulators share (row,col) per (lane,reg) -> LSTM epilogue runs in
// fragment registers; h_t/c_t written directly (no Y workspace, no 2nd kernel).
// XOR-swizzled LDS (r4: conflicts 2.8e7 -> 0) on both A and B tiles.
__global__ __launch_bounds__(256, 2) void srulstm_fused(
    const u16* __restrict__ blob,
    const float* __restrict__ c_prev,
    const float* __restrict__ bi, const float* __restrict__ bfv,
    const float* __restrict__ bo, const float* __restrict__ bxs,
    const float* __restrict__ bxg, const float* __restrict__ bhg,
    float* __restrict__ out)
{
    __shared__ __align__(16) u16 As[128 * 64];       // 16 KB
    __shared__ __align__(16) u16 Bs[5 * 64 * 64];    // 40 KB

    const u16* x   = blob + OB_X;
    const u16* h   = blob + OB_H;

    const int t = threadIdx.x;
    const int j0 = blockIdx.x * 64;    // 16 j-slices
    const int m0 = blockIdx.y * 128;   // 32 m-tiles

    // weight row-block bases (rows j0..j0+63)
    const u16* w0   = blob + OB_WI  + j0 * 2048;
    const u16* w1   = blob + OB_WF  + j0 * 2048;
    const u16* w2   = blob + OB_WO  + j0 * 2048;
    const u16* w3lo = blob + OB_WXG + j0 * 1024;
    const u16* w3hi = blob + OB_WHG + j0 * 1024;
    const u16* w4   = blob + OB_WXS + j0 * 1024;

    const u16* aLo = x + m0 * 1024;
    const u16* aHi = h + m0 * 1024;

    const int lane = t & 63;
    const int wave = t >> 6;
    const int wm = (wave >> 1) << 6;   // 0 / 64
    const int wn = (wave & 1) << 5;    // 0 / 32
    const int fr = lane & 15;
    const int fq = lane >> 4;
    const int r7 = fr & 7;             // swizzle key for fragment reads

    f32x4 acc[5][4][2] = {};           // [seg][mi][ni]

    const int er = t >> 3;             // staging row within 32-row chunk
    const int gsw = (((t & 7) ^ (er & 7)) << 3);   // swizzled source granule

    for (int k0 = 0; k0 < 2048; k0 += 64) {
        const u16* aSrc = ((k0 < 1024) ? aLo : aHi) + (k0 & 1023);
#pragma unroll
        for (int it = 0; it < 4; ++it) {
            const int row = it * 32 + er;
            __builtin_amdgcn_global_load_lds(
                (AS1 void*)(aSrc + row * 1024 + gsw),
                (AS3 void*)(As + (it * 256 + t) * 8), 16, 0, 0);
        }
        stageB(Bs,         w0 + k0, 2048, t, er, gsw);
        stageB(Bs + 4096,  w1 + k0, 2048, t, er, gsw);
        stageB(Bs + 8192,  w2 + k0, 2048, t, er, gsw);
        stageB(Bs + 12288, (k0 < 1024) ? (w3lo + k0) : (w3hi + (k0 - 1024)),
               1024, t, er, gsw);
        if (k0 < 1024)
            stageB(Bs + 16384, w4 + k0, 1024, t, er, gsw);
        __syncthreads();
#pragma unroll
        for (int kk = 0; kk < 64; kk += 32) {
            const int sw = ((((kk >> 3) + fq) ^ r7) << 3);
            bf16x8 a[4];
#pragma unroll
            for (int mi = 0; mi < 4; ++mi)
                a[mi] = *(const bf16x8*)(As + (wm + mi * 16 + fr) * 64 + sw);
#pragma unroll
            for (int s = 0; s < 4; ++s) {
                bf16x8 b0 = *(const bf16x8*)(Bs + s * 4096 + (wn + fr) * 64 + sw);
                bf16x8 b1 = *(const bf16x8*)(Bs + s * 4096 + (wn + 16 + fr) * 64 + sw);
#pragma unroll
                for (int mi = 0; mi < 4; ++mi) {
                    acc[s][mi][0] = __builtin_amdgcn_mfma_f32_16x16x32_bf16(
                        a[mi], b0, acc[s][mi][0], 0, 0, 0);
                    acc[s][mi][1] = __builtin_amdgcn_mfma_f32_16x16x32_bf16(
                        a[mi], b1, acc[s][mi][1], 0, 0, 0);
                }
            }
            if (k0 < 1024) {           // seg 4 (Wxs) has K=1024
                bf16x8 b0 = *(const bf16x8*)(Bs + 16384 + (wn + fr) * 64 + sw);
                bf16x8 b1 = *(const bf16x8*)(Bs + 16384 + (wn + 16 + fr) * 64 + sw);
#pragma unroll
                for (int mi = 0; mi < 4; ++mi) {
                    acc[4][mi][0] = __builtin_amdgcn_mfma_f32_16x16x32_bf16(
                        a[mi], b0, acc[4][mi][0], 0, 0, 0);
                    acc[4][mi][1] = __builtin_amdgcn_mfma_f32_16x16x32_bf16(
                        a[mi], b1, acc[4][mi][1], 0, 0, 0);
                }
            }
        }
        __syncthreads();
    }

    // ---- in-register LSTM epilogue ----
    // C/D layout (m89): lane holds D[m=fq*4+r][n=fr]; all 5 segs aligned.
    const int orow = m0 + wm + (fq << 2);
    const int ocol = j0 + wn + fr;
#pragma unroll
    for (int ni = 0; ni < 2; ++ni) {
        const int col = ocol + ni * 16;
        const float bi_v = bi[col],  bf_v = bfv[col], bo_v = bo[col];
        const float bs_v = bxs[col], bg_v = bxg[col], bh_v = bhg[col];
#pragma unroll
        for (int mi = 0; mi < 4; ++mi) {
#pragma unroll
            for (int r = 0; r < 4; ++r) {
                const long idx = (long)(orow + mi * 16 + r) * 1024 + col;
                const float cp = c_prev[idx];
                const float i_t = sigf(acc[0][mi][ni][r] + bi_v);
                const float f_t = sigf(acc[1][mi][ni][r] + bf_v);
                const float o_t = sigf(acc[2][mi][ni][r] + bo_v);
                const float cand = acc[3][mi][ni][r] + bg_v + bh_v;
                const float s_t  = acc[4][mi][ni][r] + bs_v;
                const float g_t = tanhf(s_t * cand);
                const float c_t = f_t * cp + i_t * g_t;
                const float h_t = o_t * tanhf(c_t);
                out[idx] = h_t;                    // h_t
                out[4194304L + idx] = c_t;         // c_t
            }
        }
    }
}

extern "C" void kernel_launch(void* const* d_in, const int* in_sizes, int n_in,
                              void* d_out, int out_size, void* d_ws, size_t ws_size,
                              hipStream_t stream)
{
    u16* blob = (u16*)d_ws;            // 35.7 MB
    float* out = (float*)d_out;

    const long convBlocks = BLOB_EL / 8 / 256;     // 8704

    convert_all<<<dim3(convBlocks), dim3(256), 0, stream>>>(
        (const float*)d_in[0], (const float*)d_in[1], (const float*)d_in[3],
        (const float*)d_in[5], (const float*)d_in[7], (const float*)d_in[9],
        (const float*)d_in[11], (const float*)d_in[13], blob);

    srulstm_fused<<<dim3(16, 32), dim3(256), 0, stream>>>(
        blob, (const float*)d_in[2], (const float*)d_in[4], (const float*)d_in[6],
        (const float*)d_in[8], (const float*)d_in[10], (const float*)d_in[12],
        (const float*)d_in[14], out);
}

// Round 7
// 222.050 us; speedup vs baseline: 1.8047x; 1.0165x over previous
//
#include <hip/hip_runtime.h>

typedef unsigned short u16;
typedef __attribute__((ext_vector_type(8))) __bf16 bf16x8;
typedef __attribute__((ext_vector_type(4))) float f32x4;
typedef __attribute__((ext_vector_type(4))) unsigned short u16x4;

#define AS1 __attribute__((address_space(1)))
#define AS3 __attribute__((address_space(3)))

// blob layout (u16 element offsets) -- bf16 copies of GEMM inputs
#define OB_X    0L
#define OB_H    4194304L
#define OB_WI   8388608L
#define OB_WF   10485760L
#define OB_WO   12582912L
#define OB_WXS  14680064L
#define OB_WXG  15728640L
#define OB_WHG  16777216L
#define BLOB_EL 17825792L

__device__ __forceinline__ u16 f2b(float f) {
    unsigned u = __float_as_uint(f);
    u += 0x7fffu + ((u >> 16) & 1u);   // round-to-nearest-even
    return (u16)(u >> 16);
}

// ---------------- f32 -> bf16 blob build (verified) ----------------
__global__ __launch_bounds__(256) void convert_all(
    const float* __restrict__ x, const float* __restrict__ h,
    const float* __restrict__ Wi, const float* __restrict__ Wf,
    const float* __restrict__ Wo, const float* __restrict__ Wxs,
    const float* __restrict__ Wxg, const float* __restrict__ Whg,
    u16* __restrict__ blob)
{
    long e = ((long)blockIdx.x * 256 + threadIdx.x) * 8;
    const float* src; long off;
    if      (e < OB_H)   { src = x;   off = e; }
    else if (e < OB_WI)  { src = h;   off = e - OB_H; }
    else if (e < OB_WF)  { src = Wi;  off = e - OB_WI; }
    else if (e < OB_WO)  { src = Wf;  off = e - OB_WF; }
    else if (e < OB_WXS) { src = Wo;  off = e - OB_WO; }
    else if (e < OB_WXG) { src = Wxs; off = e - OB_WXS; }
    else if (e < OB_WHG) { src = Wxg; off = e - OB_WXG; }
    else                 { src = Whg; off = e - OB_WHG; }
    f32x4 v0 = *(const f32x4*)(src + off);
    f32x4 v1 = *(const f32x4*)(src + off + 4);
    u16x4 o0, o1;
    o0.x = f2b(v0.x); o0.y = f2b(v0.y); o0.z = f2b(v0.z); o0.w = f2b(v0.w);
    o1.x = f2b(v1.x); o1.y = f2b(v1.y); o1.z = f2b(v1.z); o1.w = f2b(v1.w);
    *(u16x4*)(blob + e) = o0;
    *(u16x4*)(blob + e + 4) = o1;
}

// stage one 64-row x 64-col B segment (8 KB): 512 threads x 16 B, one shot
__device__ __forceinline__ void stageB(u16* dst, const u16* src, int ld,
                                       int t, int er, int gsw) {
    __builtin_amdgcn_global_load_lds(
        (AS1 void*)(src + er * ld + gsw),
        (AS3 void*)(dst + t * 8), 16, 0, 0);
}

__device__ __forceinline__ float sigf(float z) {
    return 1.f / (1.f + __expf(-z));
}

// ---------------- fully-fused SRU-LSTM cell ----------------
// Same verified 128m x 64j x 5seg single-buffer structure as the 225.7us
// control, but 8 waves (512 threads) instead of 4:
//   per-wave tile 64x32 -> 32x32, acc 160 -> 80 f32/thread (~268 -> ~180
//   unified regs/wave). Register bracket (waves halve at 64/128/256) now
//   allows 4 waves/SIMD; LDS 56KB allows 2 blocks/CU -> 16 waves/CU vs the
//   measured ~6-7 (Occupancy 19-23%). Round-0 counters showed every pipe at
//   ~1/3 (MFMA 33, VALU 27, LDS 36%, HBM 16%) = latency-bound; occupancy is
//   the binding resource and acc size is what sets it.
// Staging re-indexed for 512 threads (identical discipline; this geometry
// passed verification in round 1). Sync/swizzle/fragment/epilogue unchanged.
__global__ __launch_bounds__(512, 2) void srulstm_fused(
    const u16* __restrict__ blob,
    const float* __restrict__ c_prev,
    const float* __restrict__ bi, const float* __restrict__ bfv,
    const float* __restrict__ bo, const float* __restrict__ bxs,
    const float* __restrict__ bxg, const float* __restrict__ bhg,
    float* __restrict__ out)
{
    __shared__ __align__(16) u16 As[128 * 64];       // 16 KB
    __shared__ __align__(16) u16 Bs[5 * 64 * 64];    // 40 KB

    const u16* x   = blob + OB_X;
    const u16* h   = blob + OB_H;

    const int t = threadIdx.x;
    const int j0 = blockIdx.x * 64;    // 16 j-slices
    const int m0 = blockIdx.y * 128;   // 32 m-tiles

    // weight row-block bases (rows j0..j0+63)
    const u16* w0   = blob + OB_WI  + j0 * 2048;
    const u16* w1   = blob + OB_WF  + j0 * 2048;
    const u16* w2   = blob + OB_WO  + j0 * 2048;
    const u16* w3lo = blob + OB_WXG + j0 * 1024;
    const u16* w3hi = blob + OB_WHG + j0 * 1024;
    const u16* w4   = blob + OB_WXS + j0 * 1024;

    const u16* aLo = x + m0 * 1024;
    const u16* aHi = h + m0 * 1024;

    const int lane = t & 63;
    const int wave = t >> 6;           // 0..7
    const int wm = (wave >> 1) << 5;   // 0/32/64/96
    const int wn = (wave & 1) << 5;    // 0/32
    const int fr = lane & 15;
    const int fq = lane >> 4;
    const int r7 = fr & 7;             // swizzle key for fragment reads

    f32x4 acc[5][2][2] = {};           // [seg][mi][ni] -- 80 f32/thread

    const int er = t >> 3;             // staging row in 64-row chunk (0..63)
    const int gsw = (((t & 7) ^ (er & 7)) << 3);   // swizzled source granule

    for (int k0 = 0; k0 < 2048; k0 += 64) {
        const u16* aSrc = ((k0 < 1024) ? aLo : aHi) + (k0 & 1023);
#pragma unroll
        for (int it = 0; it < 2; ++it) {
            const int row = it * 64 + er;
            __builtin_amdgcn_global_load_lds(
                (AS1 void*)(aSrc + row * 1024 + gsw),
                (AS3 void*)(As + (it * 512 + t) * 8), 16, 0, 0);
        }
        stageB(Bs,         w0 + k0, 2048, t, er, gsw);
        stageB(Bs + 4096,  w1 + k0, 2048, t, er, gsw);
        stageB(Bs + 8192,  w2 + k0, 2048, t, er, gsw);
        stageB(Bs + 12288, (k0 < 1024) ? (w3lo + k0) : (w3hi + (k0 - 1024)),
               1024, t, er, gsw);
        if (k0 < 1024)
            stageB(Bs + 16384, w4 + k0, 1024, t, er, gsw);
        __syncthreads();
#pragma unroll
        for (int kk = 0; kk < 64; kk += 32) {
            const int sw = ((((kk >> 3) + fq) ^ r7) << 3);
            bf16x8 a[2];
#pragma unroll
            for (int mi = 0; mi < 2; ++mi)
                a[mi] = *(const bf16x8*)(As + (wm + mi * 16 + fr) * 64 + sw);
#pragma unroll
            for (int s = 0; s < 4; ++s) {
                bf16x8 b0 = *(const bf16x8*)(Bs + s * 4096 + (wn + fr) * 64 + sw);
                bf16x8 b1 = *(const bf16x8*)(Bs + s * 4096 + (wn + 16 + fr) * 64 + sw);
#pragma unroll
                for (int mi = 0; mi < 2; ++mi) {
                    acc[s][mi][0] = __builtin_amdgcn_mfma_f32_16x16x32_bf16(
                        a[mi], b0, acc[s][mi][0], 0, 0, 0);
                    acc[s][mi][1] = __builtin_amdgcn_mfma_f32_16x16x32_bf16(
                        a[mi], b1, acc[s][mi][1], 0, 0, 0);
                }
            }
            if (k0 < 1024) {           // seg 4 (Wxs) has K=1024
                bf16x8 b0 = *(const bf16x8*)(Bs + 16384 + (wn + fr) * 64 + sw);
                bf16x8 b1 = *(const bf16x8*)(Bs + 16384 + (wn + 16 + fr) * 64 + sw);
#pragma unroll
                for (int mi = 0; mi < 2; ++mi) {
                    acc[4][mi][0] = __builtin_amdgcn_mfma_f32_16x16x32_bf16(
                        a[mi], b0, acc[4][mi][0], 0, 0, 0);
                    acc[4][mi][1] = __builtin_amdgcn_mfma_f32_16x16x32_bf16(
                        a[mi], b1, acc[4][mi][1], 0, 0, 0);
                }
            }
        }
        __syncthreads();
    }

    // ---- in-register LSTM epilogue ----
    // C/D layout (m89): lane holds D[m=fq*4+r][n=fr]; all 5 segs aligned.
    const int orow = m0 + wm + (fq << 2);
    const int ocol = j0 + wn + fr;
#pragma unroll
    for (int ni = 0; ni < 2; ++ni) {
        const int col = ocol + ni * 16;
        const float bi_v = bi[col],  bf_v = bfv[col], bo_v = bo[col];
        const float bs_v = bxs[col], bg_v = bxg[col], bh_v = bhg[col];
#pragma unroll
        for (int mi = 0; mi < 2; ++mi) {
#pragma unroll
            for (int r = 0; r < 4; ++r) {
                const long idx = (long)(orow + mi * 16 + r) * 1024 + col;
                const float cp = c_prev[idx];
                const float i_t = sigf(acc[0][mi][ni][r] + bi_v);
                const float f_t = sigf(acc[1][mi][ni][r] + bf_v);
                const float o_t = sigf(acc[2][mi][ni][r] + bo_v);
                const float cand = acc[3][mi][ni][r] + bg_v + bh_v;
                const float s_t  = acc[4][mi][ni][r] + bs_v;
                const float g_t = tanhf(s_t * cand);
                const float c_t = f_t * cp + i_t * g_t;
                const float h_t = o_t * tanhf(c_t);
                out[idx] = h_t;                    // h_t
                out[4194304L + idx] = c_t;         // c_t
            }
        }
    }
}

extern "C" void kernel_launch(void* const* d_in, const int* in_sizes, int n_in,
                              void* d_out, int out_size, void* d_ws, size_t ws_size,
                              hipStream_t stream)
{
    u16* blob = (u16*)d_ws;            // 35.7 MB
    float* out = (float*)d_out;

    const long convBlocks = BLOB_EL / 8 / 256;     // 8704

    convert_all<<<dim3(convBlocks), dim3(256), 0, stream>>>(
        (const float*)d_in[0], (const float*)d_in[1], (const float*)d_in[3],
        (const float*)d_in[5], (const float*)d_in[7], (const float*)d_in[9],
        (const float*)d_in[11], (const float*)d_in[13], blob);

    srulstm_fused<<<dim3(16, 32), dim3(512), 0, stream>>>(
        blob, (const float*)d_in[2], (const float*)d_in[4], (const float*)d_in[6],
        (const float*)d_in[8], (const float*)d_in[10], (const float*)d_in[12],
        (const float*)d_in[14], out);
}